// Round 1
// baseline (1523.988 us; speedup 1.0000x reference)
//
#include <hip/hip_runtime.h>
#include <stdint.h>

typedef unsigned short u16;
typedef unsigned int u32;

// ---- problem constants ----
// B=128 S=128 WL=16 V=50000 C=100 T=17 WE=300 CE=50 CF=50 K=3 H=256 D=350
#define NPOS 16384          // B*S
#define KPAD 384            // D padded to multiple of 64
#define GDIM 1024           // 4*H
#define HD 256              // H

typedef __attribute__((ext_vector_type(8))) short bf16x8;
typedef __attribute__((ext_vector_type(4))) float f32x4;

__device__ __forceinline__ float bf2f(u16 u) { return __uint_as_float(((u32)u) << 16); }
__device__ __forceinline__ u16 f2bf(float f) {
    u32 u = __float_as_uint(f);
    u += 0x7fffu + ((u >> 16) & 1u);   // RNE
    return (u16)(u >> 16);
}
__device__ __forceinline__ float sigm(float x) { return 1.0f / (1.0f + __expf(-x)); }
__device__ __forceinline__ float tanh_(float x) { return 2.0f / (1.0f + __expf(-2.0f * x)) - 1.0f; }

// ---- workspace layout (bytes) ----
static constexpr size_t OFF_INP  = 0;                       // u16 [16384][384]   = 12582912
static constexpr size_t OFF_WIH  = 12582912;                // u16 [2048][384]    = 1572864
static constexpr size_t OFF_WHH  = 14155776;                // u16 packed 1MB
static constexpr size_t OFF_XG   = 15204352;                // u16 [16384][2048]  = 67108864
static constexpr size_t OFF_HS   = 82313216;                // u16 [16384][512]   = 16777216
static constexpr size_t OFF_EMIS = 99090432;                // f32 [16384][17]    = 1114112
static constexpr size_t OFF_HX   = 100204544;               // u16 [2][2][4][32][256] = 262144
static constexpr size_t OFF_CNT  = 100466688;               // u32 [8*16] (padded) = 1024
static constexpr size_t OFF_NLL  = 100467712;               // f32 [128]

// ============================================================
// Prep: pack [w_ih_f; w_ih_b] into bf16 [2048][384] (K padded w/ zeros)
// ============================================================
__global__ __launch_bounds__(128) void k_prep_wih(const float* __restrict__ wf,
                                                  const float* __restrict__ wb,
                                                  u16* __restrict__ wih) {
    int n = blockIdx.x, tid = threadIdx.x;
    const float* src = (n < 1024) ? (wf + (size_t)n * 350) : (wb + (size_t)(n - 1024) * 350);
    u16* dst = wih + (size_t)n * KPAD;
    for (int k = tid; k < KPAD; k += 128) dst[k] = (k < 350) ? f2bf(src[k]) : (u16)0;
}

// ============================================================
// Prep: pack w_hh (both dirs) bf16, reordered per-cluster-slice:
// dst[d][slice][wave][gate][r][k^swz], so each LSTM WG stages one contiguous 128KB chunk.
// ============================================================
__global__ __launch_bounds__(128) void k_prep_whh(const float* __restrict__ wf,
                                                  const float* __restrict__ wb,
                                                  u16* __restrict__ whh) {
    int bx = blockIdx.x, tid = threadIdx.x;
    int d = bx >> 10, row = bx & 1023;                 // row = gate*256 + hid
    const float* src = (d ? wb : wf) + (size_t)row * HD;
    int g = row >> 8, hid = row & 255;
    int s = hid >> 6, w = (hid >> 4) & 3, r = hid & 15;
    u16* dst = whh + ((((size_t)((d * 4 + s) * 4 + w) * 4 + g) * 16 + r) * 256);
    for (int k = tid; k < 256; k += 128) dst[k ^ ((r & 7) << 3)] = f2bf(src[k]);
}

// ============================================================
// Embedding + char conv + concat -> inp bf16 [16384][384]
// ============================================================
__global__ __launch_bounds__(128) void k_embed_conv(const int* __restrict__ words,
                                                    const int* __restrict__ chars,
                                                    const float* __restrict__ word_emb,
                                                    const float* __restrict__ char_emb,
                                                    const float* __restrict__ conv_w,
                                                    const float* __restrict__ conv_b,
                                                    u16* __restrict__ inp) {
    int pos = blockIdx.x, tid = threadIdx.x;
    __shared__ float ce[18 * 50];                      // rows 0 and 17 are zero pad
    const int* ch = chars + (size_t)pos * 16;
    for (int i = tid; i < 18 * 50; i += 128) {
        int row = i / 50, c = i - row * 50;
        float v = 0.f;
        if (row >= 1 && row <= 16) v = char_emb[(size_t)ch[row - 1] * 50 + c];
        ce[i] = v;
    }
    __syncthreads();
    {   // word embedding copy + zero pad
        const float* we = word_emb + (size_t)words[pos] * 300;
        u16* op = inp + (size_t)pos * KPAD;
        for (int c = tid; c < 300; c += 128) op[c] = f2bf(we[c]);
        for (int c = 350 + tid; c < KPAD; c += 128) op[c] = 0;
    }
    if (tid < 100) {
        int oc = tid >> 1, half = tid & 1, t0 = half * 8;
        float acc[8];
#pragma unroll
        for (int tt = 0; tt < 8; ++tt) acc[tt] = 0.f;
        const float* wrow = conv_w + (size_t)oc * 150;
        for (int ic = 0; ic < 50; ++ic) {
#pragma unroll
            for (int k = 0; k < 3; ++k) {
                float wv = wrow[ic * 3 + k];
#pragma unroll
                for (int tt = 0; tt < 8; ++tt)
                    acc[tt] = fmaf(ce[(t0 + tt + k) * 50 + ic], wv, acc[tt]);
            }
        }
        float cb = conv_b[oc];
        float m = 0.f;                                  // relu floor
#pragma unroll
        for (int tt = 0; tt < 8; ++tt) m = fmaxf(m, acc[tt] + cb);
        m = fmaxf(m, __shfl_xor(m, 1));
        if (half == 0) inp[(size_t)pos * KPAD + 300 + oc] = f2bf(m);
    }
}

// ============================================================
// GEMM: xg[16384][2048] = inp[16384][384] @ wih[2048][384]^T  (bf16 MFMA)
// 128x128 tile, BK=64, 4 waves (2x2), XOR-swizzled LDS
// ============================================================
__global__ __launch_bounds__(256, 2) void k_gemm(const u16* __restrict__ A,
                                                 const u16* __restrict__ Bm,
                                                 u16* __restrict__ C) {
    __shared__ u16 sa[128 * 64];
    __shared__ u16 sb[128 * 64];
    int tid = threadIdx.x;
    int n0 = blockIdx.x * 128, m0 = blockIdx.y * 128;
    int lane = tid & 63, wid = tid >> 6;
    int wr = wid >> 1, wc = wid & 1;
    f32x4 acc[4][4];
#pragma unroll
    for (int mt = 0; mt < 4; ++mt)
#pragma unroll
        for (int nt = 0; nt < 4; ++nt) acc[mt][nt] = (f32x4){0.f, 0.f, 0.f, 0.f};

    for (int kt = 0; kt < 6; ++kt) {
#pragma unroll
        for (int c = 0; c < 4; ++c) {
            int idx = (c * 256 + tid) * 16;            // byte within 16KB tile
            int row = idx >> 7, colb = idx & 127;
            int dst = idx ^ ((row & 7) << 4);
            uint4 va = *(const uint4*)((const char*)A + (size_t)(m0 + row) * 768 + kt * 128 + colb);
            *(uint4*)((char*)sa + dst) = va;
            uint4 vb = *(const uint4*)((const char*)Bm + (size_t)(n0 + row) * 768 + kt * 128 + colb);
            *(uint4*)((char*)sb + dst) = vb;
        }
        __syncthreads();
#pragma unroll
        for (int kc = 0; kc < 2; ++kc) {
            bf16x8 af[4], bf[4];
#pragma unroll
            for (int mt = 0; mt < 4; ++mt) {
                int row = wr * 64 + mt * 16 + (lane & 15);
                int off = (row * 128 + kc * 64 + (lane >> 4) * 16) ^ ((row & 7) << 4);
                af[mt] = *(const bf16x8*)((const char*)sa + off);
            }
#pragma unroll
            for (int nt = 0; nt < 4; ++nt) {
                int row = wc * 64 + nt * 16 + (lane & 15);
                int off = (row * 128 + kc * 64 + (lane >> 4) * 16) ^ ((row & 7) << 4);
                bf[nt] = *(const bf16x8*)((const char*)sb + off);
            }
#pragma unroll
            for (int mt = 0; mt < 4; ++mt)
#pragma unroll
                for (int nt = 0; nt < 4; ++nt)
                    acc[mt][nt] = __builtin_amdgcn_mfma_f32_16x16x32_bf16(af[mt], bf[nt], acc[mt][nt], 0, 0, 0);
        }
        __syncthreads();
    }
#pragma unroll
    for (int mt = 0; mt < 4; ++mt)
#pragma unroll
        for (int nt = 0; nt < 4; ++nt) {
            int col = n0 + wc * 64 + nt * 16 + (lane & 15);
#pragma unroll
            for (int r = 0; r < 4; ++r) {
                int rowg = m0 + wr * 64 + mt * 16 + (lane >> 4) * 4 + r;
                C[(size_t)rowg * 2048 + col] = f2bf(acc[mt][nt][r]);
            }
        }
}

// ============================================================
// BiLSTM recurrence. 32 WGs = dir(2) x group(4, Mtile=32) x slice(4, 64 hidden each).
// w_hh slice lives in 128KB LDS (1 WG/CU -> all 32 co-resident). Cluster (same dir,group)
// exchanges h via double-buffered global + agent-scope counter sync per step.
// ============================================================
__global__ __launch_bounds__(256, 1) void k_lstm(const u16* __restrict__ xg,
                                                 const u16* __restrict__ whh_r,
                                                 const float* __restrict__ b_f,
                                                 const float* __restrict__ b_b,
                                                 const int* __restrict__ lengths,
                                                 u16* __restrict__ hx,
                                                 u32* __restrict__ cnt,
                                                 u16* __restrict__ hs) {
    extern __shared__ u16 wl[];                        // 65536 u16 = 128KB
    int tid = threadIdx.x, lane = tid & 63, wave = tid >> 6;
    int bx = blockIdx.x;
    int slice = bx & 3, group = (bx >> 2) & 3, d = bx >> 4;

    const u16* src = whh_r + (size_t)(d * 4 + slice) * 65536;
    for (int i = tid * 8; i < 65536; i += 256 * 8)
        *(uint4*)(wl + i) = *(const uint4*)(src + i);
    __syncthreads();

    int r15 = lane & 15, hi = lane >> 4;
    int hglob = slice * 64 + wave * 16 + r15;          // hidden unit this lane's gates map to
    const float* bias = d ? b_b : b_f;
    float bi = bias[hglob], bfr_ = bias[256 + hglob], bgg = bias[512 + hglob], bo = bias[768 + hglob];

    int len_r[2][4];
    float cst[2][4], hst[2][4];
#pragma unroll
    for (int mt = 0; mt < 2; ++mt)
#pragma unroll
        for (int r = 0; r < 4; ++r) {
            len_r[mt][r] = lengths[group * 32 + mt * 16 + hi * 4 + r];
            cst[mt][r] = 0.f; hst[mt][r] = 0.f;
        }
    u32 cid = (u32)(d * 4 + group);

    for (int t = 0; t < 128; ++t) {
        int cur = t & 1;
        const u16* hxc = hx + (size_t)(((cur * 2 + d) * 4 + group) * 32) * 256;
        u16* hxn = hx + (size_t)((((1 - cur) * 2 + d) * 4 + group) * 32) * 256;

        bf16x8 af[2][8];
#pragma unroll
        for (int mt = 0; mt < 2; ++mt)
#pragma unroll
            for (int kc = 0; kc < 8; ++kc)
                af[mt][kc] = *(const bf16x8*)(hxc + (mt * 16 + r15) * 256 + kc * 32 + hi * 8);

        f32x4 acc[2][4];
#pragma unroll
        for (int mt = 0; mt < 2; ++mt)
#pragma unroll
            for (int g = 0; g < 4; ++g) acc[mt][g] = (f32x4){0.f, 0.f, 0.f, 0.f};

#pragma unroll
        for (int g = 0; g < 4; ++g)
#pragma unroll
            for (int kc = 0; kc < 8; ++kc) {
                int off = (((wave * 4 + g) * 16 + r15) * 256) + ((kc * 32 + hi * 8) ^ ((r15 & 7) << 3));
                bf16x8 bfrag = *(const bf16x8*)(wl + off);
                acc[0][g] = __builtin_amdgcn_mfma_f32_16x16x32_bf16(af[0][kc], bfrag, acc[0][g], 0, 0, 0);
                acc[1][g] = __builtin_amdgcn_mfma_f32_16x16x32_bf16(af[1][kc], bfrag, acc[1][g], 0, 0, 0);
            }

#pragma unroll
        for (int mt = 0; mt < 2; ++mt)
#pragma unroll
            for (int r = 0; r < 4; ++r) {
                int len = len_r[mt][r];
                int bl = mt * 16 + hi * 4 + r;
                int bg_ = group * 32 + bl;
                int p = d ? ((t < len) ? (len - 1 - t) : t) : t;
                size_t xbase = ((size_t)(bg_ * 128 + p)) * 2048 + (size_t)d * 1024 + hglob;
                float xi = bf2f(xg[xbase]);
                float xf = bf2f(xg[xbase + 256]);
                float xgg = bf2f(xg[xbase + 512]);
                float xo = bf2f(xg[xbase + 768]);
                float gi = sigm(acc[mt][0][r] + xi + bi);
                float gf = sigm(acc[mt][1][r] + xf + bfr_);
                float gg = tanh_(acc[mt][2][r] + xgg + bgg);
                float go = sigm(acc[mt][3][r] + xo + bo);
                float cn = gf * cst[mt][r] + gi * gg;
                float hn = go * tanh_(cn);
                if (t < len) {
                    cst[mt][r] = cn; hst[mt][r] = hn;
                    int pout = d ? (len - 1 - t) : t;
                    hs[((size_t)(bg_ * 128 + pout)) * 512 + (size_t)d * 256 + hglob] = f2bf(hn);
                }
                hxn[bl * 256 + hglob] = f2bf(hst[mt][r]);
            }

        // cluster sync (4 WGs share the h for this dir+group)
        __threadfence();
        __syncthreads();
        if (tid == 0) {
            __hip_atomic_fetch_add(&cnt[cid * 16], 1u, __ATOMIC_RELEASE, __HIP_MEMORY_SCOPE_AGENT);
            u32 target = 4u * (u32)(t + 1);
            while (__hip_atomic_load(&cnt[cid * 16], __ATOMIC_ACQUIRE, __HIP_MEMORY_SCOPE_AGENT) < target)
                __builtin_amdgcn_s_sleep(1);
        }
        __syncthreads();
    }
}

// ============================================================
// Emissions: emis[pos][17] = hs[pos][512] . proj_w[17][512] + proj_b
// ============================================================
__global__ __launch_bounds__(256) void k_emis(const u16* __restrict__ hs,
                                              const float* __restrict__ proj_w,
                                              const float* __restrict__ proj_b,
                                              float* __restrict__ emis) {
    __shared__ float pw[17 * 512];
    int tid = threadIdx.x;
    for (int i = tid; i < 17 * 512; i += 256) pw[i] = proj_w[i];
    __syncthreads();
    int lane = tid & 63, wv = tid >> 6;
    int pos = blockIdx.x * 4 + wv;
    float hv[8];
    const u16* hp = hs + (size_t)pos * 512 + lane * 8;
#pragma unroll
    for (int j = 0; j < 8; ++j) hv[j] = bf2f(hp[j]);
    for (int tg = 0; tg < 17; ++tg) {
        const float* wp = pw + tg * 512 + lane * 8;
        float s = 0.f;
#pragma unroll
        for (int j = 0; j < 8; ++j) s = fmaf(hv[j], wp[j], s);
#pragma unroll
        for (int off = 32; off; off >>= 1) s += __shfl_down(s, off);
        if (lane == 0) emis[(size_t)pos * 17 + tg] = s + proj_b[tg];
    }
}

// ============================================================
// CRF per-sample NLL. One 64-thread block per batch element.
// ============================================================
__global__ __launch_bounds__(64) void k_crf(const float* __restrict__ emis,
                                            const int* __restrict__ tags,
                                            const int* __restrict__ lengths,
                                            const float* __restrict__ trans,
                                            const float* __restrict__ start_trans,
                                            const float* __restrict__ end_trans,
                                            float* __restrict__ nll) {
    int b = blockIdx.x, lane = threadIdx.x;
    __shared__ float tr[289];
    __shared__ float al[17];
    __shared__ float scs;
    for (int i = lane; i < 289; i += 64) tr[i] = trans[i];
    int len = lengths[b];
    const int* tg = tags + (size_t)b * 128;
    const float* em = emis + (size_t)b * 128 * 17;
    __syncthreads();

    float sc = 0.f;
    for (int t = lane; t < len; t += 64) {
        sc += em[t * 17 + tg[t]];
        if (t >= 1) sc += tr[tg[t - 1] * 17 + tg[t]];
    }
#pragma unroll
    for (int off = 32; off; off >>= 1) sc += __shfl_down(sc, off);
    if (lane == 0) scs = sc + start_trans[tg[0]] + end_trans[tg[len - 1]];

    if (lane < 17) al[lane] = start_trans[lane] + em[lane];
    __syncthreads();
    for (int t = 1; t < len; ++t) {
        float anew = 0.f;
        if (lane < 17) {
            float m = -1e30f;
            for (int i = 0; i < 17; ++i) m = fmaxf(m, al[i] + tr[i * 17 + lane]);
            float s = 0.f;
            for (int i = 0; i < 17; ++i) s += __expf(al[i] + tr[i * 17 + lane] - m);
            anew = m + __logf(s) + em[t * 17 + lane];
        }
        __syncthreads();
        if (lane < 17) al[lane] = anew;
        __syncthreads();
    }
    float v = (lane < 17) ? al[lane] + end_trans[lane] : -1e30f;
    float m = v;
#pragma unroll
    for (int off = 32; off; off >>= 1) m = fmaxf(m, __shfl_xor(m, off));
    float s = (lane < 17) ? __expf(v - m) : 0.f;
#pragma unroll
    for (int off = 32; off; off >>= 1) s += __shfl_xor(s, off);
    if (lane == 0) nll[b] = (m + __logf(s)) - scs;
}

__global__ __launch_bounds__(128) void k_reduce(const float* __restrict__ nll, float* __restrict__ out) {
    int tid = threadIdx.x;
    float v = nll[tid];
#pragma unroll
    for (int off = 32; off; off >>= 1) v += __shfl_down(v, off);
    __shared__ float partial[2];
    if ((tid & 63) == 0) partial[tid >> 6] = v;
    __syncthreads();
    if (tid == 0) out[0] = partial[0] + partial[1];
}

// ============================================================
extern "C" void kernel_launch(void* const* d_in, const int* in_sizes, int n_in,
                              void* d_out, int out_size, void* d_ws, size_t ws_size,
                              hipStream_t stream) {
    (void)in_sizes; (void)n_in; (void)out_size; (void)ws_size;
    const int*   words       = (const int*)d_in[0];
    const int*   chars       = (const int*)d_in[1];
    const int*   tags        = (const int*)d_in[2];
    const int*   lengths     = (const int*)d_in[3];
    const float* word_emb    = (const float*)d_in[4];
    const float* char_emb    = (const float*)d_in[5];
    const float* conv_w      = (const float*)d_in[6];
    const float* conv_b      = (const float*)d_in[7];
    const float* w_ih_f      = (const float*)d_in[8];
    const float* w_hh_f      = (const float*)d_in[9];
    const float* b_f         = (const float*)d_in[10];
    const float* w_ih_b      = (const float*)d_in[11];
    const float* w_hh_b      = (const float*)d_in[12];
    const float* b_b         = (const float*)d_in[13];
    const float* proj_w      = (const float*)d_in[14];
    const float* proj_b      = (const float*)d_in[15];
    const float* trans       = (const float*)d_in[16];
    const float* start_trans = (const float*)d_in[17];
    const float* end_trans   = (const float*)d_in[18];

    char* ws = (char*)d_ws;
    u16* inp  = (u16*)(ws + OFF_INP);
    u16* wih  = (u16*)(ws + OFF_WIH);
    u16* whh  = (u16*)(ws + OFF_WHH);
    u16* xgb  = (u16*)(ws + OFF_XG);
    u16* hsb  = (u16*)(ws + OFF_HS);
    float* em = (float*)(ws + OFF_EMIS);
    u16* hx   = (u16*)(ws + OFF_HX);
    u32* cnt  = (u32*)(ws + OFF_CNT);
    float* nll = (float*)(ws + OFF_NLL);

    hipMemsetAsync(ws + OFF_HX, 0, (OFF_NLL - OFF_HX), stream);  // hx + cnt

    k_prep_wih<<<2048, 128, 0, stream>>>(w_ih_f, w_ih_b, wih);
    k_prep_whh<<<2048, 128, 0, stream>>>(w_hh_f, w_hh_b, whh);
    k_embed_conv<<<NPOS, 128, 0, stream>>>(words, chars, word_emb, char_emb, conv_w, conv_b, inp);
    k_gemm<<<dim3(16, 128), 256, 0, stream>>>(inp, wih, xgb);
    k_lstm<<<32, 256, 131072, stream>>>(xgb, whh, b_f, b_b, lengths, hx, cnt, hsb);
    k_emis<<<4096, 256, 0, stream>>>(hsb, proj_w, proj_b, em);
    k_crf<<<128, 64, 0, stream>>>(em, tags, lengths, trans, start_trans, end_trans, nll);
    k_reduce<<<1, 128, 0, stream>>>(nll, (float*)d_out);
}

// Round 2
// 1000.688 us; speedup vs baseline: 1.5229x; 1.5229x over previous
//
#include <hip/hip_runtime.h>
#include <stdint.h>

typedef unsigned short u16;
typedef unsigned int u32;
typedef unsigned long long u64;

// ---- problem constants ----
// B=128 S=128 WL=16 V=50000 C=100 T=17 WE=300 CE=50 CF=50 K=3 H=256 D=350
#define NPOS 16384          // B*S
#define KPAD 384            // D padded to multiple of 64
#define HD 256              // H

typedef __attribute__((ext_vector_type(8))) short bf16x8;
typedef __attribute__((ext_vector_type(4))) float f32x4;

__device__ __forceinline__ float bf2f(u16 u) { return __uint_as_float(((u32)u) << 16); }
__device__ __forceinline__ u16 f2bf(float f) {
    u32 u = __float_as_uint(f);
    u += 0x7fffu + ((u >> 16) & 1u);   // RNE
    return (u16)(u >> 16);
}
__device__ __forceinline__ float sigm(float x) { return 1.0f / (1.0f + __expf(-x)); }
__device__ __forceinline__ float tanh_(float x) { return 2.0f / (1.0f + __expf(-2.0f * x)) - 1.0f; }

// ---- workspace layout (bytes) ----
static constexpr size_t OFF_INP  = 0;                       // u16 [16384][384]   = 12582912
static constexpr size_t OFF_WIH  = 12582912;                // u16 [2048][384]    = 1572864
static constexpr size_t OFF_WHH  = 14155776;                // u16 packed 1MB
static constexpr size_t OFF_XG   = 15204352;                // u16 [16384][2048]  = 67108864  (layout: [pos][dir][hid][gate])
static constexpr size_t OFF_HS   = 82313216;                // u16 [16384][512]   = 16777216
static constexpr size_t OFF_EMIS = 99090432;                // f32 [16384][17]    = 1114112
static constexpr size_t OFF_HX   = 100204544;               // u16 [2][2][4][32][256] = 262144
static constexpr size_t OFF_CNT  = 100466688;               // u32 flags, 1024 B
static constexpr size_t OFF_NLL  = 100467712;               // f32 [128]

// ============================================================
// Prep: pack [w_ih_f; w_ih_b] into bf16 [2048][384] (K padded w/ zeros)
// ============================================================
__global__ __launch_bounds__(128) void k_prep_wih(const float* __restrict__ wf,
                                                  const float* __restrict__ wb,
                                                  u16* __restrict__ wih) {
    int n = blockIdx.x, tid = threadIdx.x;
    const float* src = (n < 1024) ? (wf + (size_t)n * 350) : (wb + (size_t)(n - 1024) * 350);
    u16* dst = wih + (size_t)n * KPAD;
    for (int k = tid; k < KPAD; k += 128) dst[k] = (k < 350) ? f2bf(src[k]) : (u16)0;
}

// ============================================================
// Prep: pack w_hh (both dirs) bf16, reordered per-cluster-slice:
// dst[d][slice][wave][gate][r][k^swz]
// ============================================================
__global__ __launch_bounds__(128) void k_prep_whh(const float* __restrict__ wf,
                                                  const float* __restrict__ wb,
                                                  u16* __restrict__ whh) {
    int bx = blockIdx.x, tid = threadIdx.x;
    int d = bx >> 10, row = bx & 1023;                 // row = gate*256 + hid
    const float* src = (d ? wb : wf) + (size_t)row * HD;
    int g = row >> 8, hid = row & 255;
    int s = hid >> 6, w = (hid >> 4) & 3, r = hid & 15;
    u16* dst = whh + ((((size_t)((d * 4 + s) * 4 + w) * 4 + g) * 16 + r) * 256);
    for (int k = tid; k < 256; k += 128) dst[k ^ ((r & 7) << 3)] = f2bf(src[k]);
}

// ============================================================
// Embedding + char conv + concat -> inp bf16 [16384][384]
// ============================================================
__global__ __launch_bounds__(128) void k_embed_conv(const int* __restrict__ words,
                                                    const int* __restrict__ chars,
                                                    const float* __restrict__ word_emb,
                                                    const float* __restrict__ char_emb,
                                                    const float* __restrict__ conv_w,
                                                    const float* __restrict__ conv_b,
                                                    u16* __restrict__ inp) {
    int pos = blockIdx.x, tid = threadIdx.x;
    __shared__ float ce[18 * 50];                      // rows 0 and 17 are zero pad
    const int* ch = chars + (size_t)pos * 16;
    for (int i = tid; i < 18 * 50; i += 128) {
        int row = i / 50, c = i - row * 50;
        float v = 0.f;
        if (row >= 1 && row <= 16) v = char_emb[(size_t)ch[row - 1] * 50 + c];
        ce[i] = v;
    }
    __syncthreads();
    {   // word embedding copy + zero pad
        const float* we = word_emb + (size_t)words[pos] * 300;
        u16* op = inp + (size_t)pos * KPAD;
        for (int c = tid; c < 300; c += 128) op[c] = f2bf(we[c]);
        for (int c = 350 + tid; c < KPAD; c += 128) op[c] = 0;
    }
    if (tid < 100) {
        int oc = tid >> 1, half = tid & 1, t0 = half * 8;
        float acc[8];
#pragma unroll
        for (int tt = 0; tt < 8; ++tt) acc[tt] = 0.f;
        const float* wrow = conv_w + (size_t)oc * 150;
        for (int ic = 0; ic < 50; ++ic) {
#pragma unroll
            for (int k = 0; k < 3; ++k) {
                float wv = wrow[ic * 3 + k];
#pragma unroll
                for (int tt = 0; tt < 8; ++tt)
                    acc[tt] = fmaf(ce[(t0 + tt + k) * 50 + ic], wv, acc[tt]);
            }
        }
        float cb = conv_b[oc];
        float m = 0.f;                                  // relu floor
#pragma unroll
        for (int tt = 0; tt < 8; ++tt) m = fmaxf(m, acc[tt] + cb);
        m = fmaxf(m, __shfl_xor(m, 1));
        if (half == 0) inp[(size_t)pos * KPAD + 300 + oc] = f2bf(m);
    }
}

// ============================================================
// GEMM: xg = inp[16384][384] @ wih[2048][384]^T  (bf16 MFMA)
// Output repacked: xg[pos][dir][hid][gate] so LSTM reads 4 gates as one u64.
// ============================================================
__global__ __launch_bounds__(256, 2) void k_gemm(const u16* __restrict__ A,
                                                 const u16* __restrict__ Bm,
                                                 u16* __restrict__ C) {
    __shared__ u16 sa[128 * 64];
    __shared__ u16 sb[128 * 64];
    int tid = threadIdx.x;
    int n0 = blockIdx.x * 128, m0 = blockIdx.y * 128;
    int lane = tid & 63, wid = tid >> 6;
    int wr = wid >> 1, wc = wid & 1;
    f32x4 acc[4][4];
#pragma unroll
    for (int mt = 0; mt < 4; ++mt)
#pragma unroll
        for (int nt = 0; nt < 4; ++nt) acc[mt][nt] = (f32x4){0.f, 0.f, 0.f, 0.f};

    for (int kt = 0; kt < 6; ++kt) {
#pragma unroll
        for (int c = 0; c < 4; ++c) {
            int idx = (c * 256 + tid) * 16;            // byte within 16KB tile
            int row = idx >> 7, colb = idx & 127;
            int dst = idx ^ ((row & 7) << 4);
            uint4 va = *(const uint4*)((const char*)A + (size_t)(m0 + row) * 768 + kt * 128 + colb);
            *(uint4*)((char*)sa + dst) = va;
            uint4 vb = *(const uint4*)((const char*)Bm + (size_t)(n0 + row) * 768 + kt * 128 + colb);
            *(uint4*)((char*)sb + dst) = vb;
        }
        __syncthreads();
#pragma unroll
        for (int kc = 0; kc < 2; ++kc) {
            bf16x8 af[4], bf[4];
#pragma unroll
            for (int mt = 0; mt < 4; ++mt) {
                int row = wr * 64 + mt * 16 + (lane & 15);
                int off = (row * 128 + kc * 64 + (lane >> 4) * 16) ^ ((row & 7) << 4);
                af[mt] = *(const bf16x8*)((const char*)sa + off);
            }
#pragma unroll
            for (int nt = 0; nt < 4; ++nt) {
                int row = wc * 64 + nt * 16 + (lane & 15);
                int off = (row * 128 + kc * 64 + (lane >> 4) * 16) ^ ((row & 7) << 4);
                bf[nt] = *(const bf16x8*)((const char*)sb + off);
            }
#pragma unroll
            for (int mt = 0; mt < 4; ++mt)
#pragma unroll
                for (int nt = 0; nt < 4; ++nt)
                    acc[mt][nt] = __builtin_amdgcn_mfma_f32_16x16x32_bf16(af[mt], bf[nt], acc[mt][nt], 0, 0, 0);
        }
        __syncthreads();
    }
#pragma unroll
    for (int mt = 0; mt < 4; ++mt)
#pragma unroll
        for (int nt = 0; nt < 4; ++nt) {
            int col = n0 + wc * 64 + nt * 16 + (lane & 15);
            int dd = col >> 10, rem = col & 1023;
            int newcol = (dd << 10) + ((rem & 255) << 2) + (rem >> 8);
#pragma unroll
            for (int r = 0; r < 4; ++r) {
                int rowg = m0 + wr * 64 + mt * 16 + (lane >> 4) * 4 + r;
                C[(size_t)rowg * 2048 + newcol] = f2bf(acc[mt][nt][r]);
            }
        }
}

// ============================================================
// BiLSTM recurrence. 32 WGs = dir(2) x group(4, Mtile=32) x slice(4, 64 hidden each).
// w_hh slice in 128KB LDS. Cross-WG h exchange via agent-scope (LLC write-through)
// relaxed atomics + per-WG step flags. No threadfence/wbl2, no acquire-RMW spin.
// ============================================================
__global__ __launch_bounds__(256, 1) void k_lstm(const u16* __restrict__ xg,
                                                 const u16* __restrict__ whh_r,
                                                 const float* __restrict__ b_f,
                                                 const float* __restrict__ b_b,
                                                 const int* __restrict__ lengths,
                                                 u16* __restrict__ hx,
                                                 u32* __restrict__ flags,
                                                 u16* __restrict__ hs) {
    __shared__ u16 hstage[32 * 64];                    // 4KB h staging for coalesced LLC stores
    extern __shared__ u16 wl[];                        // 65536 u16 = 128KB
    int tid = threadIdx.x, lane = tid & 63, wave = tid >> 6;
    int bx = blockIdx.x;
    int slice = bx & 3, group = (bx >> 2) & 3, d = bx >> 4;

    const u16* src = whh_r + (size_t)(d * 4 + slice) * 65536;
    for (int i = tid * 8; i < 65536; i += 2048)
        *(uint4*)(wl + i) = *(const uint4*)(src + i);
    __syncthreads();

    int r15 = lane & 15, hi = lane >> 4;
    int hglob = slice * 64 + wave * 16 + r15;          // hidden unit this lane's gates map to
    const float* bias = d ? b_b : b_f;
    float bi = bias[hglob], bfr = bias[256 + hglob], bgg = bias[512 + hglob], bo = bias[768 + hglob];

    int len_r[2][4];
    float cst[2][4], hstv[2][4];
#pragma unroll
    for (int mt = 0; mt < 2; ++mt)
#pragma unroll
        for (int r = 0; r < 4; ++r) {
            len_r[mt][r] = lengths[group * 32 + mt * 16 + hi * 4 + r];
            cst[mt][r] = 0.f; hstv[mt][r] = 0.f;
        }
    int fbase = (d * 4 + group) * 4;                   // flag idx = (fbase+slice)*4 (16B apart)

    // xg prefetch registers (4 gates packed per u64), t=0
    u64 xq[2][4];
#pragma unroll
    for (int mt = 0; mt < 2; ++mt)
#pragma unroll
        for (int r = 0; r < 4; ++r) {
            int len = len_r[mt][r];
            int bg_ = group * 32 + mt * 16 + hi * 4 + r;
            int p = d ? ((0 < len) ? (len - 1) : 0) : 0;
            xq[mt][r] = *(const u64*)(xg + ((size_t)bg_ * 128 + p) * 2048 + (size_t)d * 1024 + (size_t)hglob * 4);
        }

    for (int t = 0; t < 128; ++t) {
        const u16* hxc = hx + (size_t)((((t + 1) & 1) * 2 + d) * 4 + group) * 32 * 256;
        u16* hxn = hx + (size_t)(((t & 1) * 2 + d) * 4 + group) * 32 * 256;

        bf16x8 af[2][8];
        if (t == 0) {
#pragma unroll
            for (int mt = 0; mt < 2; ++mt)
#pragma unroll
                for (int kc = 0; kc < 8; ++kc)
                    af[mt][kc] = (bf16x8){0, 0, 0, 0, 0, 0, 0, 0};
        } else {
            // acquire: pairs with peers' flag stores; invalidates stale L1/L2 copies
            __builtin_amdgcn_fence(__ATOMIC_ACQUIRE, "agent");
#pragma unroll
            for (int mt = 0; mt < 2; ++mt)
#pragma unroll
                for (int kc = 0; kc < 8; ++kc)
                    af[mt][kc] = *(const bf16x8*)(hxc + (mt * 16 + r15) * 256 + kc * 32 + hi * 8);
        }

        f32x4 acc[2][4];
#pragma unroll
        for (int mt = 0; mt < 2; ++mt)
#pragma unroll
            for (int g = 0; g < 4; ++g) acc[mt][g] = (f32x4){0.f, 0.f, 0.f, 0.f};

#pragma unroll
        for (int g = 0; g < 4; ++g)
#pragma unroll
            for (int kc = 0; kc < 8; ++kc) {
                int off = (((wave * 4 + g) * 16 + r15) * 256) + ((kc * 32 + hi * 8) ^ ((r15 & 7) << 3));
                bf16x8 bfrag = *(const bf16x8*)(wl + off);
                acc[0][g] = __builtin_amdgcn_mfma_f32_16x16x32_bf16(af[0][kc], bfrag, acc[0][g], 0, 0, 0);
                acc[1][g] = __builtin_amdgcn_mfma_f32_16x16x32_bf16(af[1][kc], bfrag, acc[1][g], 0, 0, 0);
            }

#pragma unroll
        for (int mt = 0; mt < 2; ++mt)
#pragma unroll
            for (int r = 0; r < 4; ++r) {
                int len = len_r[mt][r];
                int bl = mt * 16 + hi * 4 + r;
                int bg_ = group * 32 + bl;
                u64 xv = xq[mt][r];
                float xi  = bf2f((u16)(xv & 0xffff));
                float xf  = bf2f((u16)((xv >> 16) & 0xffff));
                float xgg = bf2f((u16)((xv >> 32) & 0xffff));
                float xo  = bf2f((u16)(xv >> 48));
                float gi = sigm(acc[mt][0][r] + xi + bi);
                float gf = sigm(acc[mt][1][r] + xf + bfr);
                float gg = tanh_(acc[mt][2][r] + xgg + bgg);
                float go = sigm(acc[mt][3][r] + xo + bo);
                float cn = gf * cst[mt][r] + gi * gg;
                float hn = go * tanh_(cn);
                if (t < len) {
                    cst[mt][r] = cn; hstv[mt][r] = hn;
                    int pout = d ? (len - 1 - t) : t;
                    hs[((size_t)bg_ * 128 + pout) * 512 + (size_t)d * 256 + hglob] = f2bf(hn);
                }
                hstage[bl * 64 + wave * 16 + r15] = f2bf(hstv[mt][r]);
            }
        __syncthreads();                               // hstage complete

        // coalesced write-through h store to LLC (agent-visible, no dirty L2)
        {
            int srow = tid >> 3, scol = (tid & 7) * 8;
            u64 hval = *(const u64*)(hstage + srow * 64 + scol);
            __hip_atomic_store((u64*)(hxn + srow * 256 + slice * 64 + scol), hval,
                               __ATOMIC_RELAXED, __HIP_MEMORY_SCOPE_AGENT);
        }
        asm volatile("s_waitcnt vmcnt(0)" ::: "memory");   // stores acked at LLC
        __syncthreads();                                    // all waves' stores done
        if (tid == 0)
            __hip_atomic_store(&flags[(size_t)(fbase + slice) * 4], (u32)(t + 1),
                               __ATOMIC_RELAXED, __HIP_MEMORY_SCOPE_AGENT);

        // prefetch xg(t+1) while waiting (normal cached loads; xg is read-only)
        if (t < 127) {
#pragma unroll
            for (int mt = 0; mt < 2; ++mt)
#pragma unroll
                for (int r = 0; r < 4; ++r) {
                    int len = len_r[mt][r];
                    int bg_ = group * 32 + mt * 16 + hi * 4 + r;
                    int tt = t + 1;
                    int p = d ? ((tt < len) ? (len - 1 - tt) : tt) : tt;
                    xq[mt][r] = *(const u64*)(xg + ((size_t)bg_ * 128 + p) * 2048 + (size_t)d * 1024 + (size_t)hglob * 4);
                }
        }

        // spin: one lane per cluster flag, relaxed LLC polls
        if (tid < 4) {
            u32 tgt = (u32)(t + 1);
            u32* fp = (u32*)&flags[(size_t)(fbase + tid) * 4];
            int guard = 0;
            while (__hip_atomic_load(fp, __ATOMIC_RELAXED, __HIP_MEMORY_SCOPE_AGENT) < tgt) {
                if (++guard > (1 << 22)) break;        // deadlock guard -> visible as absmax fail
            }
        }
        __syncthreads();
    }
}

// ============================================================
// Emissions: emis[pos][17] = hs[pos][512] . proj_w[17][512] + proj_b
// ============================================================
__global__ __launch_bounds__(256) void k_emis(const u16* __restrict__ hs,
                                              const float* __restrict__ proj_w,
                                              const float* __restrict__ proj_b,
                                              float* __restrict__ emis) {
    __shared__ float pw[17 * 512];
    int tid = threadIdx.x;
    for (int i = tid; i < 17 * 512; i += 256) pw[i] = proj_w[i];
    __syncthreads();
    int lane = tid & 63, wv = tid >> 6;
    int pos = blockIdx.x * 4 + wv;
    float hv[8];
    const u16* hp = hs + (size_t)pos * 512 + lane * 8;
#pragma unroll
    for (int j = 0; j < 8; ++j) hv[j] = bf2f(hp[j]);
    for (int tg = 0; tg < 17; ++tg) {
        const float* wp = pw + tg * 512 + lane * 8;
        float s = 0.f;
#pragma unroll
        for (int j = 0; j < 8; ++j) s = fmaf(hv[j], wp[j], s);
#pragma unroll
        for (int off = 32; off; off >>= 1) s += __shfl_down(s, off);
        if (lane == 0) emis[(size_t)pos * 17 + tg] = s + proj_b[tg];
    }
}

// ============================================================
// CRF per-sample NLL. One 64-thread block per batch element.
// ============================================================
__global__ __launch_bounds__(64) void k_crf(const float* __restrict__ emis,
                                            const int* __restrict__ tags,
                                            const int* __restrict__ lengths,
                                            const float* __restrict__ trans,
                                            const float* __restrict__ start_trans,
                                            const float* __restrict__ end_trans,
                                            float* __restrict__ nll) {
    int b = blockIdx.x, lane = threadIdx.x;
    __shared__ float tr[289];
    __shared__ float al[17];
    __shared__ float scs;
    for (int i = lane; i < 289; i += 64) tr[i] = trans[i];
    int len = lengths[b];
    const int* tg = tags + (size_t)b * 128;
    const float* em = emis + (size_t)b * 128 * 17;
    __syncthreads();

    float sc = 0.f;
    for (int t = lane; t < len; t += 64) {
        sc += em[t * 17 + tg[t]];
        if (t >= 1) sc += tr[tg[t - 1] * 17 + tg[t]];
    }
#pragma unroll
    for (int off = 32; off; off >>= 1) sc += __shfl_down(sc, off);
    if (lane == 0) scs = sc + start_trans[tg[0]] + end_trans[tg[len - 1]];

    if (lane < 17) al[lane] = start_trans[lane] + em[lane];
    __syncthreads();
    for (int t = 1; t < len; ++t) {
        float anew = 0.f;
        if (lane < 17) {
            float m = -1e30f;
            for (int i = 0; i < 17; ++i) m = fmaxf(m, al[i] + tr[i * 17 + lane]);
            float s = 0.f;
            for (int i = 0; i < 17; ++i) s += __expf(al[i] + tr[i * 17 + lane] - m);
            anew = m + __logf(s) + em[t * 17 + lane];
        }
        __syncthreads();
        if (lane < 17) al[lane] = anew;
        __syncthreads();
    }
    float v = (lane < 17) ? al[lane] + end_trans[lane] : -1e30f;
    float m = v;
#pragma unroll
    for (int off = 32; off; off >>= 1) m = fmaxf(m, __shfl_xor(m, off));
    float s = (lane < 17) ? __expf(v - m) : 0.f;
#pragma unroll
    for (int off = 32; off; off >>= 1) s += __shfl_xor(s, off);
    if (lane == 0) nll[b] = (m + __logf(s)) - scs;
}

__global__ __launch_bounds__(128) void k_reduce(const float* __restrict__ nll, float* __restrict__ out) {
    int tid = threadIdx.x;
    float v = nll[tid];
#pragma unroll
    for (int off = 32; off; off >>= 1) v += __shfl_down(v, off);
    __shared__ float partial[2];
    if ((tid & 63) == 0) partial[tid >> 6] = v;
    __syncthreads();
    if (tid == 0) out[0] = partial[0] + partial[1];
}

// ============================================================
extern "C" void kernel_launch(void* const* d_in, const int* in_sizes, int n_in,
                              void* d_out, int out_size, void* d_ws, size_t ws_size,
                              hipStream_t stream) {
    (void)in_sizes; (void)n_in; (void)out_size; (void)ws_size;
    const int*   words       = (const int*)d_in[0];
    const int*   chars       = (const int*)d_in[1];
    const int*   tags        = (const int*)d_in[2];
    const int*   lengths     = (const int*)d_in[3];
    const float* word_emb    = (const float*)d_in[4];
    const float* char_emb    = (const float*)d_in[5];
    const float* conv_w      = (const float*)d_in[6];
    const float* conv_b      = (const float*)d_in[7];
    const float* w_ih_f      = (const float*)d_in[8];
    const float* w_hh_f      = (const float*)d_in[9];
    const float* b_f         = (const float*)d_in[10];
    const float* w_ih_b      = (const float*)d_in[11];
    const float* w_hh_b      = (const float*)d_in[12];
    const float* b_b         = (const float*)d_in[13];
    const float* proj_w      = (const float*)d_in[14];
    const float* proj_b      = (const float*)d_in[15];
    const float* trans       = (const float*)d_in[16];
    const float* start_trans = (const float*)d_in[17];
    const float* end_trans   = (const float*)d_in[18];

    char* ws = (char*)d_ws;
    u16* inp  = (u16*)(ws + OFF_INP);
    u16* wih  = (u16*)(ws + OFF_WIH);
    u16* whh  = (u16*)(ws + OFF_WHH);
    u16* xgb  = (u16*)(ws + OFF_XG);
    u16* hsb  = (u16*)(ws + OFF_HS);
    float* em = (float*)(ws + OFF_EMIS);
    u16* hx   = (u16*)(ws + OFF_HX);
    u32* flg  = (u32*)(ws + OFF_CNT);
    float* nll = (float*)(ws + OFF_NLL);

    hipMemsetAsync(ws + OFF_HX, 0, (OFF_NLL - OFF_HX), stream);  // hx + flags

    k_prep_wih<<<2048, 128, 0, stream>>>(w_ih_f, w_ih_b, wih);
    k_prep_whh<<<2048, 128, 0, stream>>>(w_hh_f, w_hh_b, whh);
    k_embed_conv<<<NPOS, 128, 0, stream>>>(words, chars, word_emb, char_emb, conv_w, conv_b, inp);
    k_gemm<<<dim3(16, 128), 256, 0, stream>>>(inp, wih, xgb);
    k_lstm<<<32, 256, 131072, stream>>>(xgb, whh, b_f, b_b, lengths, hx, flg, hsb);
    k_emis<<<4096, 256, 0, stream>>>(hsb, proj_w, proj_b, em);
    k_crf<<<128, 64, 0, stream>>>(em, tags, lengths, trans, start_trans, end_trans, nll);
    k_reduce<<<1, 128, 0, stream>>>(nll, (float*)d_out);
}